// Round 2
// baseline (2085.749 us; speedup 1.0000x reference)
//
#include <hip/hip_runtime.h>
#include <hip/hip_bf16.h>
#include <cstdint>

typedef __hip_bfloat16 bf16;
typedef __attribute__((ext_vector_type(8))) short short8;   // 8 bf16 = 4 VGPRs
typedef __attribute__((ext_vector_type(4))) float f32x4;

__device__ __forceinline__ f32x4 mfma16(short8 a, short8 b, f32x4 c) {
  return __builtin_amdgcn_mfma_f32_16x16x32_bf16(a, b, c, 0, 0, 0);
}

// async global->LDS, 16B per lane; LDS dest = wave-uniform base + lane*16
__device__ __forceinline__ void gload16(const bf16* g, bf16* l) {
  __builtin_amdgcn_global_load_lds((const __attribute__((address_space(1))) void*)g,
                                   (__attribute__((address_space(3))) void*)l, 16, 0, 0);
}

// ---------------- elementwise / conversion ----------------

// vectorized: 4 f32 in, 4 bf16 out per thread
__global__ void __launch_bounds__(256) cvt_f32_bf16(const float* __restrict__ in,
                                                    bf16* __restrict__ out, int n4) {
  int i = blockIdx.x * 256 + threadIdx.x;
  if (i < n4) {
    float4 v = *(const float4*)&in[(size_t)i * 4];
    bf16 o[4] = {__float2bfloat16(v.x), __float2bfloat16(v.y),
                 __float2bfloat16(v.z), __float2bfloat16(v.w)};
    *(uint2*)&out[(size_t)i * 4] = *(uint2*)o;
  }
}

// ---------------- transposes: K x N f32 -> N x K bf16 (64x64 tiles, float4) ----

__device__ __forceinline__ void trans_tile64(float (*t)[65], const float* __restrict__ src,
                                             bf16* __restrict__ dst, int K, int N,
                                             int bx, int by) {
  int n0 = bx * 64, k0 = by * 64;
  int tx = threadIdx.x & 15, ty = threadIdx.x >> 4;   // tx: col-quad, ty: row
#pragma unroll
  for (int j = 0; j < 64; j += 16) {
    float4 v = *(const float4*)&src[(size_t)(k0 + ty + j) * N + n0 + tx * 4];
    t[ty + j][tx * 4 + 0] = v.x;
    t[ty + j][tx * 4 + 1] = v.y;
    t[ty + j][tx * 4 + 2] = v.z;
    t[ty + j][tx * 4 + 3] = v.w;
  }
  __syncthreads();
  int cb = tx * 4;
#pragma unroll
  for (int jj = 0; jj < 4; jj++) {
    int r = ty + jj * 16;
    bf16 o[4] = {__float2bfloat16(t[cb + 0][r]), __float2bfloat16(t[cb + 1][r]),
                 __float2bfloat16(t[cb + 2][r]), __float2bfloat16(t[cb + 3][r])};
    *(uint2*)&dst[(size_t)(n0 + r) * K + k0 + cb] = *(uint2*)o;
  }
}

__global__ void __launch_bounds__(256) transpose_cvt(const float* __restrict__ src,
                                                     bf16* __restrict__ dst,
                                                     int K, int N) {
  __shared__ float tile[64][65];
  trans_tile64(tile, src, dst, K, N, blockIdx.x, blockIdx.y);
}

// all 5 per-layer weights in one launch (3072 blocks of 64x64 tiles)
__global__ void __launch_bounds__(256) transpose_all(
    const float* __restrict__ wq, const float* __restrict__ wkv,
    const float* __restrict__ wo, const float* __restrict__ w1,
    const float* __restrict__ w2, bf16* __restrict__ wq_t, bf16* __restrict__ wkv_t,
    bf16* __restrict__ wo_t, bf16* __restrict__ w1_t, bf16* __restrict__ w2_t) {
  __shared__ float tile[64][65];
  int id = blockIdx.x;
  if (id < 256) {
    trans_tile64(tile, wq, wq_t, 1024, 1024, id & 15, id >> 4);
  } else if (id < 768) {
    id -= 256;
    trans_tile64(tile, wkv, wkv_t, 1024, 2048, id & 31, id >> 5);
  } else if (id < 1024) {
    id -= 768;
    trans_tile64(tile, wo, wo_t, 1024, 1024, id & 15, id >> 4);
  } else if (id < 2048) {
    id -= 1024;
    trans_tile64(tile, w1, w1_t, 1024, 4096, id & 63, id >> 6);
  } else {
    id -= 2048;
    trans_tile64(tile, w2, w2_t, 4096, 1024, id & 15, id >> 4);
  }
}

// ---------------- layernorm family (cols fixed at 1024, float4 lanes) --------

__device__ __forceinline__ void stats4(float4 v, int tid, float& mean,
                                       float& rstd, float* red) {
  float s = v.x + v.y + v.z + v.w;
  float s2 = v.x * v.x + v.y * v.y + v.z * v.z + v.w * v.w;
#pragma unroll
  for (int o = 32; o > 0; o >>= 1) {
    s += __shfl_down(s, o);
    s2 += __shfl_down(s2, o);
  }
  int w = tid >> 6;
  if ((tid & 63) == 0) { red[w] = s; red[4 + w] = s2; }
  __syncthreads();
  s = red[0] + red[1] + red[2] + red[3];
  s2 = red[4] + red[5] + red[6] + red[7];
  mean = s * (1.f / 1024.f);
  float var = s2 * (1.f / 1024.f) - mean * mean;
  rstd = rsqrtf(var + 1e-5f);
}

__device__ __forceinline__ void pack4(bf16* dst, float a, float b, float c, float d) {
  bf16 o[4] = {__float2bfloat16(a), __float2bfloat16(b),
               __float2bfloat16(c), __float2bfloat16(d)};
  *(uint2*)dst = *(uint2*)o;
}

__global__ void __launch_bounds__(256) ln_to_bf16(const float* __restrict__ in,
                                                  const float* __restrict__ g,
                                                  const float* __restrict__ bb,
                                                  bf16* __restrict__ out) {
  __shared__ float red[8];
  int row = blockIdx.x, tid = threadIdx.x, c4 = tid * 4;
  float4 v = *(const float4*)&in[(size_t)row * 1024 + c4];
  float mean, rstd;
  stats4(v, tid, mean, rstd, red);
  float y0 = (v.x - mean) * rstd, y1 = (v.y - mean) * rstd;
  float y2 = (v.z - mean) * rstd, y3 = (v.w - mean) * rstd;
  if (g) {
    float4 gv = *(const float4*)&g[c4];
    float4 bv = *(const float4*)&bb[c4];
    y0 = y0 * gv.x + bv.x; y1 = y1 * gv.y + bv.y;
    y2 = y2 * gv.z + bv.z; y3 = y3 * gv.w + bv.w;
  }
  pack4(&out[(size_t)row * 1024 + c4], y0, y1, y2, y3);
}

// cat rows per batch (336) = [xn affine(257) | LN(lat)(64) | zero pad(15)].
// Latent branch also PRODUCES lat: LM=0 -> broadcast lin; LM=1 -> sum of 2 split-K
// planes (prev layer's ff2) + lat2 residual. Writes lat (f32), cat, lnlat.
template <int LM>
__global__ void __launch_bounds__(256) lncat(const bf16* __restrict__ xhat,
                                             const float* __restrict__ lin,
                                             const float* __restrict__ parts,
                                             const float* __restrict__ lat2,
                                             float* __restrict__ lat,
                                             const float* __restrict__ g1,
                                             const float* __restrict__ b1,
                                             const float* __restrict__ g2,
                                             const float* __restrict__ b2,
                                             bf16* __restrict__ cat,
                                             bf16* __restrict__ lnlat) {
  __shared__ float red[8];
  int row = blockIdx.x, tid = threadIdx.x, c4 = tid * 4;
  int bidx = row / 336, n = row - bidx * 336;
  bf16* out = cat + (size_t)row * 1024;
  const size_t MN = (size_t)2048 * 1024;
  if (n < 257) {
    const bf16* in = xhat + ((size_t)bidx * 257 + n) * 1024;
    uint2 rw = *(const uint2*)&in[c4];
    const bf16* rb = (const bf16*)&rw;
    float4 gv = *(const float4*)&g1[c4];
    float4 bv = *(const float4*)&b1[c4];
    pack4(&out[c4], __bfloat162float(rb[0]) * gv.x + bv.x,
          __bfloat162float(rb[1]) * gv.y + bv.y,
          __bfloat162float(rb[2]) * gv.z + bv.z,
          __bfloat162float(rb[3]) * gv.w + bv.w);
  } else if (n < 321) {
    int lrow = bidx * 64 + (n - 257);
    size_t idx = (size_t)lrow * 1024 + c4;
    float4 a;
    if (LM == 0) {
      a = *(const float4*)&lin[(size_t)(n - 257) * 1024 + c4];
    } else {
      float4 p0 = *(const float4*)&parts[idx];
      float4 p1 = *(const float4*)&parts[MN + idx];
      float4 r2 = *(const float4*)&lat2[idx];
      a.x = p0.x + p1.x + r2.x; a.y = p0.y + p1.y + r2.y;
      a.z = p0.z + p1.z + r2.z; a.w = p0.w + p1.w + r2.w;
    }
    *(float4*)&lat[idx] = a;
    float mean, rstd;
    stats4(a, tid, mean, rstd, red);
    float4 gv = *(const float4*)&g2[c4];
    float4 bv = *(const float4*)&b2[c4];
    bf16 o[4] = {__float2bfloat16((a.x - mean) * rstd * gv.x + bv.x),
                 __float2bfloat16((a.y - mean) * rstd * gv.y + bv.y),
                 __float2bfloat16((a.z - mean) * rstd * gv.z + bv.z),
                 __float2bfloat16((a.w - mean) * rstd * gv.w + bv.w)};
    *(uint2*)&out[c4] = *(uint2*)o;
    *(uint2*)&lnlat[idx] = *(uint2*)o;
  } else {
    uint2 z = {0, 0};
    *(uint2*)&out[c4] = z;
  }
}

// ---------------- GEMM: C(MxN) = A(MxK,bf16) @ Bt(NxK,bf16)^T ----------------
// 128x128 tile, BK=64, 4 waves of 64x64, mfma_f32_16x16x32_bf16.
// Staging via global_load_lds width=16 (m97 2-barrier structure, barrier count
// halved vs BK=32).

enum { MB_BIAS = 1, MB_RESID = 2, MB_GELU = 4, MB_BF16 = 8 };

template <int MODE>
__device__ __forceinline__ void gemm_tile(
    const bf16* __restrict__ A, const bf16* __restrict__ Bt, void* __restrict__ Cout,
    const float* __restrict__ bias, const float* __restrict__ resid,
    int M, int N, int K, int m0, int n0, int kBeg, int kEnd, size_t planeOff,
    bf16* sA, bf16* sB) {
  int tid = threadIdx.x;
  int wave = tid >> 6, lane = tid & 63;
  int quad = lane >> 4, l16 = lane & 15;
  int wm = (wave >> 1) * 64, wn = (wave & 1) * 64;

  // staging map: issue s covers rows s*32..s*32+31; wave w rows w*8+(lane>>3)
  int srow = wave * 8 + (lane >> 3);
  int scol = (lane & 7) * 8;
  const bf16* gA[4];
  const bf16* gB[4];
#pragma unroll
  for (int s = 0; s < 4; s++) {
    gA[s] = A + (size_t)min(m0 + s * 32 + srow, M - 1) * K + scol;
    gB[s] = Bt + (size_t)(n0 + s * 32 + srow) * K + scol;
  }
  bf16* lA = &sA[(wave * 8) * 64];
  bf16* lB = &sB[(wave * 8) * 64];

  f32x4 acc[4][4] = {};

  for (int k0 = kBeg; k0 < kEnd; k0 += 64) {
#pragma unroll
    for (int s = 0; s < 4; s++) {
      gload16(gA[s] + k0, lA + s * 32 * 64);
      gload16(gB[s] + k0, lB + s * 32 * 64);
    }
    __syncthreads();   // drains vmcnt: staged data visible
    short8 af[2][4], bfv[2][4];
#pragma unroll
    for (int ks = 0; ks < 2; ks++) {
#pragma unroll
      for (int i = 0; i < 4; i++)
        af[ks][i] = *(const short8*)&sA[(wm + i * 16 + l16) * 64 + ks * 32 + quad * 8];
#pragma unroll
      for (int j = 0; j < 4; j++)
        bfv[ks][j] = *(const short8*)&sB[(wn + j * 16 + l16) * 64 + ks * 32 + quad * 8];
    }
#pragma unroll
    for (int ks = 0; ks < 2; ks++)
#pragma unroll
      for (int i = 0; i < 4; i++)
#pragma unroll
        for (int j = 0; j < 4; j++)
          acc[ks ? i : i][j] = mfma16(af[ks][i], bfv[ks][j], acc[i][j]);
    __syncthreads();   // all frag reads done before next iteration's stores
  }

  float* cf = (float*)Cout + planeOff;
#pragma unroll
  for (int i = 0; i < 4; i++) {
    int grb = m0 + wm + i * 16 + quad * 4;
#pragma unroll
    for (int j = 0; j < 4; j++) {
      int gc = n0 + wn + j * 16 + l16;
      float bv = (MODE & MB_BIAS) ? bias[gc] : 0.f;
#pragma unroll
      for (int r = 0; r < 4; r++) {
        int gr = grb + r;
        if (gr < M) {
          float vv = acc[i][j][r] + bv;
          if (MODE & MB_GELU) vv = 0.5f * vv * (1.f + erff(vv * 0.70710678118654752f));
          if (MODE & MB_RESID) vv += resid[(size_t)gr * N + gc];
          if (MODE & MB_BF16) ((bf16*)Cout)[(size_t)gr * N + gc] = __float2bfloat16(vv);
          else cf[(size_t)gr * N + gc] = vv;
        }
      }
    }
  }
}

template <int MODE>
__global__ void __launch_bounds__(256, 2) gemm_bt(
    const bf16* __restrict__ A, const bf16* __restrict__ Bt,
    void* __restrict__ Cout, const float* __restrict__ bias,
    const float* __restrict__ resid, int M, int N, int K) {
  __shared__ bf16 sA[128 * 64];
  __shared__ bf16 sB[128 * 64];
  int kPer = K / gridDim.z;
  gemm_tile<MODE>(A, Bt, Cout, bias, resid, M, N, K,
                  blockIdx.y * 128, blockIdx.x * 128,
                  blockIdx.z * kPer, (blockIdx.z + 1) * kPer,
                  (size_t)blockIdx.z * ((size_t)M * N), sA, sB);
}

// merged launch: kv = cat @ Wkv (84x16 tiles) plus q = lnlat @ Wq (128 tiles),
// both direct bf16 out, no split-K. grid (16, 92).
__global__ void __launch_bounds__(256, 2) gemm_qkv(
    const bf16* __restrict__ catb, const bf16* __restrict__ wkv,
    bf16* __restrict__ kvbuf, const bf16* __restrict__ lnlat,
    const bf16* __restrict__ wq, bf16* __restrict__ qbuf) {
  __shared__ bf16 sA[128 * 64];
  __shared__ bf16 sB[128 * 64];
  int by = blockIdx.y, bx = blockIdx.x;
  if (by < 84) {
    gemm_tile<MB_BF16>(catb, wkv, kvbuf, nullptr, nullptr, 10752, 2048, 1024,
                       by * 128, bx * 128, 0, 1024, 0, sA, sB);
  } else {
    int t = (by - 84) * 16 + bx;   // 0..127
    gemm_tile<MB_BF16>(lnlat, wq, qbuf, nullptr, nullptr, 2048, 1024, 1024,
                       (t >> 3) * 128, (t & 7) * 128, 0, 1024, 0, sA, sB);
  }
}

// ---------------- split-K reduce (+bias/resid, f32 or bf16 out) ----------------

enum { RD_BIAS = 1, RD_RESID = 2, RD_BF16 = 4 };

template <int MODE>
__global__ void __launch_bounds__(256) reduce_k(const float* __restrict__ parts, int S,
                                                int MN, int N,
                                                const float* __restrict__ bias,
                                                const float* __restrict__ resid,
                                                void* __restrict__ out) {
  int i4 = (blockIdx.x * 256 + threadIdx.x) * 4;
  if (i4 >= MN) return;
  float4 a = *(const float4*)&parts[i4];
#pragma unroll 4
  for (int s = 1; s < S; s++) {
    float4 b = *(const float4*)&parts[(size_t)s * MN + i4];
    a.x += b.x; a.y += b.y; a.z += b.z; a.w += b.w;
  }
  if (MODE & RD_BIAS) {
    float4 b = *(const float4*)&bias[i4 & (N - 1)];
    a.x += b.x; a.y += b.y; a.z += b.z; a.w += b.w;
  }
  if (MODE & RD_RESID) {
    float4 b = *(const float4*)&resid[i4];
    a.x += b.x; a.y += b.y; a.z += b.z; a.w += b.w;
  }
  if (MODE & RD_BF16) {
    bf16 o[4] = {__float2bfloat16(a.x), __float2bfloat16(a.y),
                 __float2bfloat16(a.z), __float2bfloat16(a.w)};
    *(uint2*)&((bf16*)out)[i4] = *(uint2*)o;
  } else {
    *(float4*)&((float*)out)[i4] = a;
  }
}

// fused: sum 2 split-K planes + resid(lat) -> lat2(f32), then LN -> lnff(bf16)
__global__ void __launch_bounds__(256) reduce_ln_resid(
    const float* __restrict__ parts, const float* __restrict__ resid,
    const float* __restrict__ g, const float* __restrict__ bb,
    float* __restrict__ lat2, bf16* __restrict__ lnff) {
  __shared__ float red[8];
  int row = blockIdx.x, tid = threadIdx.x, c4 = tid * 4;
  const size_t MN = (size_t)2048 * 1024;
  size_t idx = (size_t)row * 1024 + c4;
  float4 p0 = *(const float4*)&parts[idx];
  float4 p1 = *(const float4*)&parts[MN + idx];
  float4 r2 = *(const float4*)&resid[idx];
  float4 a;
  a.x = p0.x + p1.x + r2.x; a.y = p0.y + p1.y + r2.y;
  a.z = p0.z + p1.z + r2.z; a.w = p0.w + p1.w + r2.w;
  *(float4*)&lat2[idx] = a;
  float mean, rstd;
  stats4(a, tid, mean, rstd, red);
  float4 gv = *(const float4*)&g[c4];
  float4 bv = *(const float4*)&bb[c4];
  pack4(&lnff[idx], (a.x - mean) * rstd * gv.x + bv.x,
        (a.y - mean) * rstd * gv.y + bv.y,
        (a.z - mean) * rstd * gv.z + bv.z,
        (a.w - mean) * rstd * gv.w + bv.w);
}

// fused epilogue: sum 2 planes + bias -> LN(nog,nob) -> f32 out (d_out)
__global__ void __launch_bounds__(256) reduce_bias_ln(
    const float* __restrict__ parts, const float* __restrict__ bias,
    const float* __restrict__ g, const float* __restrict__ bb,
    float* __restrict__ out) {
  __shared__ float red[8];
  int row = blockIdx.x, tid = threadIdx.x, c4 = tid * 4;
  const size_t MN = (size_t)2048 * 1024;
  size_t idx = (size_t)row * 1024 + c4;
  float4 p0 = *(const float4*)&parts[idx];
  float4 p1 = *(const float4*)&parts[MN + idx];
  float4 bv = *(const float4*)&bias[c4];
  float4 a;
  a.x = p0.x + p1.x + bv.x; a.y = p0.y + p1.y + bv.y;
  a.z = p0.z + p1.z + bv.z; a.w = p0.w + p1.w + bv.w;
  float mean, rstd;
  stats4(a, tid, mean, rstd, red);
  float4 gv = *(const float4*)&g[c4];
  float4 b2 = *(const float4*)&bb[c4];
  float4 o;
  o.x = (a.x - mean) * rstd * gv.x + b2.x;
  o.y = (a.y - mean) * rstd * gv.y + b2.y;
  o.z = (a.z - mean) * rstd * gv.z + b2.z;
  o.w = (a.w - mean) * rstd * gv.w + b2.w;
  *(float4*)&out[idx] = o;
}

// ---------------- fused attention: one block per (b,h) ----------------
// q: (b*64+m, h*64+d) bf16;  kv: (b*336+r, [k: h*64+d | v: 1024+h*64+d]) bf16
// valid kv rows: 321 (rows 321..335 are zero pad); scores scaled by 1/8.
//
// LDS: sQ/sKV are [64][64] bf16 with XOR granule swizzle
// byte ^= ((row&7)<<4) ^ (((row>>3)&3)<<5); sP stride 376 elems.

__device__ __forceinline__ int swz64(int row, int cb) {
  return (row << 7) + (cb ^ ((row & 7) << 4) ^ (((row >> 3) & 3) << 5));
}

__global__ void __launch_bounds__(256, 2) attn(const bf16* __restrict__ qb,
                                               const bf16* __restrict__ kvb,
                                               bf16* __restrict__ ob) {
  __shared__ bf16 sQ[64 * 64];
  __shared__ bf16 sKV[64 * 64];
  __shared__ bf16 sP[64 * 376];   // cols 0..351 used (336..351 zero)
  __shared__ float sRed[256];
  char* cQ = (char*)sQ;
  char* cKV = (char*)sKV;

  int h = blockIdx.x, b = blockIdx.y;
  int tid = threadIdx.x, wave = tid >> 6, lane = tid & 63;
  int quad = lane >> 4, l16 = lane & 15;

  const bf16* qg = qb + (size_t)b * 64 * 1024 + h * 64;
  const bf16* kg = kvb + (size_t)b * 336 * 2048 + h * 64;
  const bf16* vg = kg + 1024;

  {
    int r = tid >> 3, cb = (tid & 7) * 16;
    *(uint4*)(cQ + swz64(r, cb)) =
        *(const uint4*)((const char*)qg + (size_t)r * 2048 + cb);
    *(uint4*)(cQ + swz64(r + 32, cb)) =
        *(const uint4*)((const char*)qg + (size_t)(r + 32) * 2048 + cb);
  }

  f32x4 accS[6][4] = {};   // [kv group of 64][m-tile]; wave owns n-tile g*4+wave

  for (int g = 0; g < 6; g++) {
    __syncthreads();
    {
      int r = tid >> 3, cb = (tid & 7) * 16;
      int gr = g * 64 + r;
      if (gr < 336)
        *(uint4*)(cKV + swz64(r, cb)) =
            *(const uint4*)((const char*)kg + (size_t)gr * 4096 + cb);
      gr += 32;
      if (gr < 336)
        *(uint4*)(cKV + swz64(r + 32, cb)) =
            *(const uint4*)((const char*)kg + (size_t)gr * 4096 + cb);
    }
    __syncthreads();
    if (g * 4 + wave < 21) {
#pragma unroll
      for (int ks = 0; ks < 2; ks++) {
        short8 bfr = *(const short8*)(cKV + swz64(wave * 16 + l16, ks * 64 + quad * 16));
#pragma unroll
        for (int i = 0; i < 4; i++) {
          short8 afr = *(const short8*)(cQ + swz64(i * 16 + l16, ks * 64 + quad * 16));
          accS[g][i] = mfma16(afr, bfr, accS[g][i]);
        }
      }
    }
  }

  // ---- softmax over 321 valid cols ----
  float rmax[4][4], rsum[4][4];
#pragma unroll
  for (int i = 0; i < 4; i++)
#pragma unroll
    for (int r = 0; r < 4; r++) { rmax[i][r] = -1e30f; rsum[i][r] = 0.f; }

#pragma unroll
  for (int g = 0; g < 6; g++) {
    int col = (g * 4 + wave) * 16 + l16;
    bool valid = col < 321;
#pragma unroll
    for (int i = 0; i < 4; i++)
#pragma unroll
      for (int r = 0; r < 4; r++) {
        float v = accS[g][i][r] * 0.125f;   // (dh^-0.25)^2
        accS[g][i][r] = v;
        if (valid) rmax[i][r] = fmaxf(rmax[i][r], v);
      }
  }
#pragma unroll
  for (int off = 1; off < 16; off <<= 1)
#pragma unroll
    for (int i = 0; i < 4; i++)
#pragma unroll
      for (int r = 0; r < 4; r++)
        rmax[i][r] = fmaxf(rmax[i][r], __shfl_xor(rmax[i][r], off));
  if (l16 == 0) {
#pragma unroll
    for (int i = 0; i < 4; i++)
#pragma unroll
      for (int r = 0; r < 4; r++)
        sRed[wave * 64 + i * 16 + quad * 4 + r] = rmax[i][r];
  }
  __syncthreads();
#pragma unroll
  for (int i = 0; i < 4; i++)
#pragma unroll
    for (int r = 0; r < 4; r++) {
      int row = i * 16 + quad * 4 + r;
      rmax[i][r] = fmaxf(fmaxf(sRed[row], sRed[64 + row]),
                         fmaxf(sRed[128 + row], sRed[192 + row]));
    }
  __syncthreads();

#pragma unroll
  for (int g = 0; g < 6; g++) {
    int col = (g * 4 + wave) * 16 + l16;
    bool valid = col < 321;
#pragma unroll
    for (int i = 0; i < 4; i++)
#pragma unroll
      for (int r = 0; r < 4; r++) {
        float pv = valid ? __expf(accS[g][i][r] - rmax[i][r]) : 0.f;
        rsum[i][r] += pv;
        if (col < 352) sP[(i * 16 + quad * 4 + r) * 376 + col] = __float2bfloat16(pv);
      }
  }
#pragma unroll
  for (int off = 1; off < 16; off <<= 1)
#pragma unroll
    for (int i = 0; i < 4; i++)
#pragma unroll
      for (int r = 0; r < 4; r++)
        rsum[i][r] += __shfl_xor(rsum[i][r], off);
  if (l16 == 0) {
#pragma unroll
    for (int i = 0; i < 4; i++)
#pragma unroll
      for (int r = 0; r < 4; r++)
        sRed[wave * 64 + i * 16 + quad * 4 + r] = rsum[i][r];
  }
  __syncthreads();
#pragma unroll
  for (int i = 0; i < 4; i++)
#pragma unroll
    for (int r = 0; r < 4; r++) {
      int row = i * 16 + quad * 4 + r;
      rsum[i][r] = sRed[row] + sRed[64 + row] + sRed[128 + row] + sRed[192 + row];
    }

  // ---- O = P @ V, wave owns dh-tile [wave*16, wave*16+16) ----
  f32x4 accO[4] = {};
  for (int cch = 0; cch < 6; cch++) {
    __syncthreads();
    {
      int r = tid >> 3, cb = (tid & 7) * 16;
      int gr = cch * 64 + r;
      if (gr < 336)
        *(uint4*)(cKV + swz64(r, cb)) =
            *(const uint4*)((const char*)vg + (size_t)gr * 4096 + cb);
      gr += 32;
      if (gr < 336)
        *(uint4*)(cKV + swz64(r + 32, cb)) =
            *(const uint4*)((const char*)vg + (size_t)gr * 4096 + cb);
    }
    __syncthreads();
    int nks = (cch == 5) ? 1 : 2;   // last chunk: P zero past col 336
    for (int ks = 0; ks < nks; ks++) {
      short8 bv;
      int cb = (wave * 16 + l16) * 2;
#pragma unroll
      for (int jj = 0; jj < 8; jj++)
        bv[jj] = *(const short*)(cKV + swz64(ks * 32 + quad * 8 + jj, cb));
#pragma unroll
      for (int i = 0; i < 4; i++) {
        short8 ap = *(const short8*)&sP[(i * 16 + l16) * 376 + cch * 64 + ks * 32 + quad * 8];
        accO[i] = mfma16(ap, bv, accO[i]);
      }
    }
  }

#pragma unroll
  for (int i = 0; i < 4; i++)
#pragma unroll
    for (int r = 0; r < 4; r++) {
      int row = i * 16 + quad * 4 + r;
      ob[(size_t)(b * 64 + row) * 1024 + h * 64 + wave * 16 + l16] =
          __float2bfloat16(accO[i][r] / rsum[i][r]);
    }
}

// ---------------- host orchestration ----------------

extern "C" void kernel_launch(void* const* d_in, const int* in_sizes, int n_in,
                              void* d_out, int out_size, void* d_ws, size_t ws_size,
                              hipStream_t stream) {
  (void)in_sizes; (void)n_in; (void)out_size; (void)ws_size;
  const float* x    = (const float*)d_in[0];
  const float* lin  = (const float*)d_in[1];
  const float* piw  = (const float*)d_in[2];
  const float* pib  = (const float*)d_in[3];
  const float* ln1g = (const float*)d_in[4];
  const float* ln1b = (const float*)d_in[5];
  const float* ln2g = (const float*)d_in[6];
  const float* ln2b = (const float*)d_in[7];
  const float* Wq   = (const float*)d_in[8];
  const float* Wkv  = (const float*)d_in[9];
  const float* Wo   = (const float*)d_in[10];
  const float* ffg  = (const float*)d_in[11];
  const float* ffb  = (const float*)d_in[12];
  const float* W1   = (const float*)d_in[13];
  const float* W2   = (const float*)d_in[14];
  const float* poW  = (const float*)d_in[15];
  const float* pob  = (const float*)d_in[16];
  const float* nog  = (const float*)d_in[17];
  const float* nob  = (const float*)d_in[18];

  char* p = (char*)d_ws;
  auto alloc = [&](size_t bytes) -> char* {
    char* q = p; p += (bytes + 255) & ~(size_t)255; return q;
  };
  bf16* pin_t  = (bf16*)alloc((size_t)1024 * 768 * 2);
  bf16* pout_t = (bf16*)alloc((size_t)1024 * 1024 * 2);
  bf16* wq_t   = (bf16*)alloc((size_t)1024 * 1024 * 2);
  bf16* wkv_t  = (bf16*)alloc((size_t)2048 * 1024 * 2);
  bf16* wo_t   = (bf16*)alloc((size_t)1024 * 1024 * 2);
  bf16* w1_t   = (bf16*)alloc((size_t)4096 * 1024 * 2);
  bf16* w2_t   = (bf16*)alloc((size_t)1024 * 4096 * 2);
  bf16* x_bf   = (bf16*)alloc((size_t)8224 * 768 * 2);
  float* xf    = (float*)alloc((size_t)8224 * 1024 * 4);   // prologue xf; later: split-K partials
  bf16* xhat   = (bf16*)alloc((size_t)8224 * 1024 * 2);
  bf16* cat    = (bf16*)alloc((size_t)10752 * 1024 * 2);   // 32 x 336 rows
  bf16* lnlat  = (bf16*)alloc((size_t)2048 * 1024 * 2);
  bf16* qbuf   = (bf16*)alloc((size_t)2048 * 1024 * 2);
  bf16* kvbuf  = (bf16*)alloc((size_t)10752 * 2048 * 2);
  bf16* obuf   = (bf16*)alloc((size_t)2048 * 1024 * 2);
  float* lat   = (float*)alloc((size_t)2048 * 1024 * 4);
  float* lat2  = (float*)alloc((size_t)2048 * 1024 * 4);
  bf16* lnff   = (bf16*)alloc((size_t)2048 * 1024 * 2);
  bf16* h1     = (bf16*)alloc((size_t)2048 * 4096 * 2);

  const int MN = 2048 * 1024;   // split-K partial plane size

  // prologue
  cvt_f32_bf16<<<(6316032 / 4 + 255) / 256, 256, 0, stream>>>(x, x_bf, 6316032 / 4);
  transpose_cvt<<<dim3(16, 12), 256, 0, stream>>>(piw, pin_t, 768, 1024);
  transpose_cvt<<<dim3(16, 16), 256, 0, stream>>>(poW, pout_t, 1024, 1024);
  gemm_bt<MB_BIAS><<<dim3(8, 65), 256, 0, stream>>>(x_bf, pin_t, xf, pib, nullptr,
                                                    8224, 1024, 768);
  ln_to_bf16<<<8224, 256, 0, stream>>>(xf, nullptr, nullptr, xhat);

  for (int i = 0; i < 8; i++) {
    transpose_all<<<3072, 256, 0, stream>>>(
        Wq + (size_t)i * 1048576, Wkv + (size_t)i * 2097152, Wo + (size_t)i * 1048576,
        W1 + (size_t)i * 4194304, W2 + (size_t)i * 4194304,
        wq_t, wkv_t, wo_t, w1_t, w2_t);
    // lncat: layer 0 broadcasts lin -> lat; layers 1..7 also reduce prev ff2 planes
    if (i == 0)
      lncat<0><<<10752, 256, 0, stream>>>(xhat, lin, nullptr, nullptr, lat,
                                          ln1g + i * 1024, ln1b + i * 1024,
                                          ln2g + i * 1024, ln2b + i * 1024, cat, lnlat);
    else
      lncat<1><<<10752, 256, 0, stream>>>(xhat, nullptr, xf, lat2, lat,
                                          ln1g + i * 1024, ln1b + i * 1024,
                                          ln2g + i * 1024, ln2b + i * 1024, cat, lnlat);
    // kv = cat @ Wkv  (+ q = lnlat @ Wq appended as 128 extra tiles)
    gemm_qkv<<<dim3(16, 92), 256, 0, stream>>>(cat, wkv_t, kvbuf, lnlat, wq_t, qbuf);
    attn<<<dim3(16, 32), 256, 0, stream>>>(qbuf, kvbuf, obuf);
    // lat2 = o @ Wo + lat  (split-K=2), fused with ff-LN -> lnff
    gemm_bt<0><<<dim3(8, 16, 2), 256, 0, stream>>>(obuf, wo_t, xf, nullptr, nullptr,
                                                   2048, 1024, 1024);
    reduce_ln_resid<<<2048, 256, 0, stream>>>(xf, lat, ffg + i * 1024, ffb + i * 1024,
                                              lat2, lnff);
    gemm_bt<MB_GELU | MB_BF16><<<dim3(32, 16), 256, 0, stream>>>(lnff, w1_t, h1, nullptr,
                                                                 nullptr, 2048, 4096, 1024);
    // lat = h1 @ W2 + lat2  (split-K=2, Kper=2048); planes consumed by next lncat
    gemm_bt<0><<<dim3(8, 16, 2), 256, 0, stream>>>(h1, w2_t, xf, nullptr, nullptr,
                                                   2048, 1024, 4096);
    if (i == 7)   // final layer: fold reduce+resid straight to bf16 lnff
      reduce_k<RD_RESID | RD_BF16><<<MN / 1024, 256, 0, stream>>>(
          xf, 2, MN, 1024, nullptr, lat2, lnff);
  }

  // epilogue: proj_out + bias + final LN fused
  gemm_bt<0><<<dim3(8, 16, 2), 256, 0, stream>>>(lnff, pout_t, xf, nullptr, nullptr,
                                                 2048, 1024, 1024);
  reduce_bias_ln<<<2048, 256, 0, stream>>>(xf, pob, nog, nob, (float*)d_out);
}

// Round 3
// 1991.088 us; speedup vs baseline: 1.0475x; 1.0475x over previous
//
#include <hip/hip_runtime.h>
#include <hip/hip_bf16.h>
#include <cstdint>

typedef __hip_bfloat16 bf16;
typedef __attribute__((ext_vector_type(8))) short short8;   // 8 bf16 = 4 VGPRs
typedef __attribute__((ext_vector_type(4))) float f32x4;

__device__ __forceinline__ f32x4 mfma16(short8 a, short8 b, f32x4 c) {
  return __builtin_amdgcn_mfma_f32_16x16x32_bf16(a, b, c, 0, 0, 0);
}

// async global->LDS, 16B per lane; LDS dest = wave-uniform base + lane*16
__device__ __forceinline__ void gload16(const bf16* g, bf16* l) {
  __builtin_amdgcn_global_load_lds((const __attribute__((address_space(1))) void*)g,
                                   (__attribute__((address_space(3))) void*)l, 16, 0, 0);
}

// ---------------- elementwise / conversion ----------------

// vectorized: 4 f32 in, 4 bf16 out per thread
__global__ void __launch_bounds__(256) cvt_f32_bf16(const float* __restrict__ in,
                                                    bf16* __restrict__ out, int n4) {
  int i = blockIdx.x * 256 + threadIdx.x;
  if (i < n4) {
    float4 v = *(const float4*)&in[(size_t)i * 4];
    bf16 o[4] = {__float2bfloat16(v.x), __float2bfloat16(v.y),
                 __float2bfloat16(v.z), __float2bfloat16(v.w)};
    *(uint2*)&out[(size_t)i * 4] = *(uint2*)o;
  }
}

// ---------------- transposes: K x N f32 -> N x K bf16 (64x64 tiles, float4) ----

__device__ __forceinline__ void trans_tile64(float (*t)[65], const float* __restrict__ src,
                                             bf16* __restrict__ dst, int K, int N,
                                             int bx, int by) {
  int n0 = bx * 64, k0 = by * 64;
  int tx = threadIdx.x & 15, ty = threadIdx.x >> 4;   // tx: col-quad, ty: row
#pragma unroll
  for (int j = 0; j < 64; j += 16) {
    float4 v = *(const float4*)&src[(size_t)(k0 + ty + j) * N + n0 + tx * 4];
    t[ty + j][tx * 4 + 0] = v.x;
    t[ty + j][tx * 4 + 1] = v.y;
    t[ty + j][tx * 4 + 2] = v.z;
    t[ty + j][tx * 4 + 3] = v.w;
  }
  __syncthreads();
  int cb = tx * 4;
#pragma unroll
  for (int jj = 0; jj < 4; jj++) {
    int r = ty + jj * 16;
    bf16 o[4] = {__float2bfloat16(t[cb + 0][r]), __float2bfloat16(t[cb + 1][r]),
                 __float2bfloat16(t[cb + 2][r]), __float2bfloat16(t[cb + 3][r])};
    *(uint2*)&dst[(size_t)(n0 + r) * K + k0 + cb] = *(uint2*)o;
  }
}

__global__ void __launch_bounds__(256) transpose_cvt(const float* __restrict__ src,
                                                     bf16* __restrict__ dst,
                                                     int K, int N) {
  __shared__ float tile[64][65];
  trans_tile64(tile, src, dst, K, N, blockIdx.x, blockIdx.y);
}

// all 5 per-layer weights in one launch (3072 blocks of 64x64 tiles)
__global__ void __launch_bounds__(256) transpose_all(
    const float* __restrict__ wq, const float* __restrict__ wkv,
    const float* __restrict__ wo, const float* __restrict__ w1,
    const float* __restrict__ w2, bf16* __restrict__ wq_t, bf16* __restrict__ wkv_t,
    bf16* __restrict__ wo_t, bf16* __restrict__ w1_t, bf16* __restrict__ w2_t) {
  __shared__ float tile[64][65];
  int id = blockIdx.x;
  if (id < 256) {
    trans_tile64(tile, wq, wq_t, 1024, 1024, id & 15, id >> 4);
  } else if (id < 768) {
    id -= 256;
    trans_tile64(tile, wkv, wkv_t, 1024, 2048, id & 31, id >> 5);
  } else if (id < 1024) {
    id -= 768;
    trans_tile64(tile, wo, wo_t, 1024, 1024, id & 15, id >> 4);
  } else if (id < 2048) {
    id -= 1024;
    trans_tile64(tile, w1, w1_t, 1024, 4096, id & 63, id >> 6);
  } else {
    id -= 2048;
    trans_tile64(tile, w2, w2_t, 4096, 1024, id & 15, id >> 4);
  }
}

// ---------------- layernorm family (cols fixed at 1024, float4 lanes) --------

__device__ __forceinline__ void stats4(float4 v, int tid, float& mean,
                                       float& rstd, float* red) {
  float s = v.x + v.y + v.z + v.w;
  float s2 = v.x * v.x + v.y * v.y + v.z * v.z + v.w * v.w;
#pragma unroll
  for (int o = 32; o > 0; o >>= 1) {
    s += __shfl_down(s, o);
    s2 += __shfl_down(s2, o);
  }
  int w = tid >> 6;
  if ((tid & 63) == 0) { red[w] = s; red[4 + w] = s2; }
  __syncthreads();
  s = red[0] + red[1] + red[2] + red[3];
  s2 = red[4] + red[5] + red[6] + red[7];
  mean = s * (1.f / 1024.f);
  float var = s2 * (1.f / 1024.f) - mean * mean;
  rstd = rsqrtf(var + 1e-5f);
}

__device__ __forceinline__ void pack4(bf16* dst, float a, float b, float c, float d) {
  bf16 o[4] = {__float2bfloat16(a), __float2bfloat16(b),
               __float2bfloat16(c), __float2bfloat16(d)};
  *(uint2*)dst = *(uint2*)o;
}

__global__ void __launch_bounds__(256) ln_to_bf16(const float* __restrict__ in,
                                                  const float* __restrict__ g,
                                                  const float* __restrict__ bb,
                                                  bf16* __restrict__ out) {
  __shared__ float red[8];
  int row = blockIdx.x, tid = threadIdx.x, c4 = tid * 4;
  float4 v = *(const float4*)&in[(size_t)row * 1024 + c4];
  float mean, rstd;
  stats4(v, tid, mean, rstd, red);
  float y0 = (v.x - mean) * rstd, y1 = (v.y - mean) * rstd;
  float y2 = (v.z - mean) * rstd, y3 = (v.w - mean) * rstd;
  if (g) {
    float4 gv = *(const float4*)&g[c4];
    float4 bv = *(const float4*)&bb[c4];
    y0 = y0 * gv.x + bv.x; y1 = y1 * gv.y + bv.y;
    y2 = y2 * gv.z + bv.z; y3 = y3 * gv.w + bv.w;
  }
  pack4(&out[(size_t)row * 1024 + c4], y0, y1, y2, y3);
}

// cat rows per batch (336) = [xn affine(257) | LN(lat)(64) | zero pad(15)].
// Latent branch also PRODUCES lat: LM=0 -> broadcast lin; LM=1 -> sum of 4 split-K
// planes (prev layer's ff2) + lat2 residual. Writes lat (f32), cat, lnlat.
template <int LM>
__global__ void __launch_bounds__(256) lncat(const bf16* __restrict__ xhat,
                                             const float* __restrict__ lin,
                                             const float* __restrict__ parts,
                                             const float* __restrict__ lat2,
                                             float* __restrict__ lat,
                                             const float* __restrict__ g1,
                                             const float* __restrict__ b1,
                                             const float* __restrict__ g2,
                                             const float* __restrict__ b2,
                                             bf16* __restrict__ cat,
                                             bf16* __restrict__ lnlat) {
  __shared__ float red[8];
  int row = blockIdx.x, tid = threadIdx.x, c4 = tid * 4;
  int bidx = row / 336, n = row - bidx * 336;
  bf16* out = cat + (size_t)row * 1024;
  const size_t MN = (size_t)2048 * 1024;
  if (n < 257) {
    const bf16* in = xhat + ((size_t)bidx * 257 + n) * 1024;
    uint2 rw = *(const uint2*)&in[c4];
    const bf16* rb = (const bf16*)&rw;
    float4 gv = *(const float4*)&g1[c4];
    float4 bv = *(const float4*)&b1[c4];
    pack4(&out[c4], __bfloat162float(rb[0]) * gv.x + bv.x,
          __bfloat162float(rb[1]) * gv.y + bv.y,
          __bfloat162float(rb[2]) * gv.z + bv.z,
          __bfloat162float(rb[3]) * gv.w + bv.w);
  } else if (n < 321) {
    int lrow = bidx * 64 + (n - 257);
    size_t idx = (size_t)lrow * 1024 + c4;
    float4 a;
    if (LM == 0) {
      a = *(const float4*)&lin[(size_t)(n - 257) * 1024 + c4];
    } else {
      float4 p0 = *(const float4*)&parts[idx];
      float4 p1 = *(const float4*)&parts[MN + idx];
      float4 p2 = *(const float4*)&parts[2 * MN + idx];
      float4 p3 = *(const float4*)&parts[3 * MN + idx];
      float4 r2 = *(const float4*)&lat2[idx];
      a.x = p0.x + p1.x + p2.x + p3.x + r2.x;
      a.y = p0.y + p1.y + p2.y + p3.y + r2.y;
      a.z = p0.z + p1.z + p2.z + p3.z + r2.z;
      a.w = p0.w + p1.w + p2.w + p3.w + r2.w;
    }
    *(float4*)&lat[idx] = a;
    float mean, rstd;
    stats4(a, tid, mean, rstd, red);
    float4 gv = *(const float4*)&g2[c4];
    float4 bv = *(const float4*)&b2[c4];
    bf16 o[4] = {__float2bfloat16((a.x - mean) * rstd * gv.x + bv.x),
                 __float2bfloat16((a.y - mean) * rstd * gv.y + bv.y),
                 __float2bfloat16((a.z - mean) * rstd * gv.z + bv.z),
                 __float2bfloat16((a.w - mean) * rstd * gv.w + bv.w)};
    *(uint2*)&out[c4] = *(uint2*)o;
    *(uint2*)&lnlat[idx] = *(uint2*)o;
  } else {
    uint2 z = {0, 0};
    *(uint2*)&out[c4] = z;
  }
}

// ---------------- GEMM: C(MxN) = A(MxK,bf16) @ Bt(NxK,bf16)^T ----------------
// 128x128 tile, BK=32, 4 waves of 64x64, mfma_f32_16x16x32_bf16.
// Staging via global_load_lds width=16 (m97 2-barrier structure).
// NOTE: BK=64 and split-K S=2 both measured SLOWER (round 2: +85us) — keep
// BK=32, S=4 (512 blocks = 2/CU co-residency hides the barrier drain).

enum { MB_BIAS = 1, MB_RESID = 2, MB_GELU = 4, MB_BF16 = 8 };

template <int MODE>
__device__ __forceinline__ void gemm_tile(
    const bf16* __restrict__ A, const bf16* __restrict__ Bt, void* __restrict__ Cout,
    const float* __restrict__ bias, const float* __restrict__ resid,
    int M, int N, int K, int m0, int n0, int kBeg, int kEnd, size_t planeOff,
    bf16* sA, bf16* sB) {
  int tid = threadIdx.x;
  int wave = tid >> 6, lane = tid & 63;
  int quad = lane >> 4, l16 = lane & 15;
  int wm = (wave >> 1) * 64, wn = (wave & 1) * 64;

  // staging map: wave w, lane l -> row w*16 + (l>>2), col (l&3)*8  (+64 rows, 2nd issue)
  int srow = wave * 16 + (lane >> 2);
  int scol = (lane & 3) * 8;
  const bf16* gA0 = A + (size_t)min(m0 + srow, M - 1) * K + scol;
  const bf16* gA1 = A + (size_t)min(m0 + 64 + srow, M - 1) * K + scol;
  const bf16* gB0 = Bt + (size_t)(n0 + srow) * K + scol;
  const bf16* gB1 = Bt + (size_t)(n0 + 64 + srow) * K + scol;
  bf16* lA0 = &sA[(wave * 16) * 32];
  bf16* lA1 = &sA[(64 + wave * 16) * 32];
  bf16* lB0 = &sB[(wave * 16) * 32];
  bf16* lB1 = &sB[(64 + wave * 16) * 32];

  f32x4 acc[4][4] = {};

  for (int k0 = kBeg; k0 < kEnd; k0 += 32) {
    gload16(gA0 + k0, lA0);
    gload16(gA1 + k0, lA1);
    gload16(gB0 + k0, lB0);
    gload16(gB1 + k0, lB1);
    __syncthreads();   // drains vmcnt: staged data visible
    short8 af[4], bfv[4];
#pragma unroll
    for (int i = 0; i < 4; i++)
      af[i] = *(const short8*)&sA[(wm + i * 16 + l16) * 32 + quad * 8];
#pragma unroll
    for (int j = 0; j < 4; j++)
      bfv[j] = *(const short8*)&sB[(wn + j * 16 + l16) * 32 + quad * 8];
#pragma unroll
    for (int i = 0; i < 4; i++)
#pragma unroll
      for (int j = 0; j < 4; j++)
        acc[i][j] = mfma16(af[i], bfv[j], acc[i][j]);
    __syncthreads();   // all frag reads done before next iteration's stores
  }

  float* cf = (float*)Cout + planeOff;
#pragma unroll
  for (int i = 0; i < 4; i++) {
    int grb = m0 + wm + i * 16 + quad * 4;
#pragma unroll
    for (int j = 0; j < 4; j++) {
      int gc = n0 + wn + j * 16 + l16;
      float bv = (MODE & MB_BIAS) ? bias[gc] : 0.f;
#pragma unroll
      for (int r = 0; r < 4; r++) {
        int gr = grb + r;
        if (gr < M) {
          float vv = acc[i][j][r] + bv;
          if (MODE & MB_GELU) vv = 0.5f * vv * (1.f + erff(vv * 0.70710678118654752f));
          if (MODE & MB_RESID) vv += resid[(size_t)gr * N + gc];
          if (MODE & MB_BF16) ((bf16*)Cout)[(size_t)gr * N + gc] = __float2bfloat16(vv);
          else cf[(size_t)gr * N + gc] = vv;
        }
      }
    }
  }
}

template <int MODE>
__global__ void __launch_bounds__(256, 2) gemm_bt(
    const bf16* __restrict__ A, const bf16* __restrict__ Bt,
    void* __restrict__ Cout, const float* __restrict__ bias,
    const float* __restrict__ resid, int M, int N, int K) {
  __shared__ bf16 sA[128 * 32];
  __shared__ bf16 sB[128 * 32];
  int kPer = K / gridDim.z;
  gemm_tile<MODE>(A, Bt, Cout, bias, resid, M, N, K,
                  blockIdx.y * 128, blockIdx.x * 128,
                  blockIdx.z * kPer, (blockIdx.z + 1) * kPer,
                  (size_t)blockIdx.z * ((size_t)M * N), sA, sB);
}

// merged launch: kv = cat @ Wkv (84x16 tiles) plus q = lnlat @ Wq (128 tiles),
// both direct bf16 out, no split-K. grid (16, 92).
__global__ void __launch_bounds__(256, 2) gemm_qkv(
    const bf16* __restrict__ catb, const bf16* __restrict__ wkv,
    bf16* __restrict__ kvbuf, const bf16* __restrict__ lnlat,
    const bf16* __restrict__ wq, bf16* __restrict__ qbuf) {
  __shared__ bf16 sA[128 * 32];
  __shared__ bf16 sB[128 * 32];
  int by = blockIdx.y, bx = blockIdx.x;
  if (by < 84) {
    gemm_tile<MB_BF16>(catb, wkv, kvbuf, nullptr, nullptr, 10752, 2048, 1024,
                       by * 128, bx * 128, 0, 1024, 0, sA, sB);
  } else {
    int t = (by - 84) * 16 + bx;   // 0..127
    gemm_tile<MB_BF16>(lnlat, wq, qbuf, nullptr, nullptr, 2048, 1024, 1024,
                       (t >> 3) * 128, (t & 7) * 128, 0, 1024, 0, sA, sB);
  }
}

// ---------------- split-K reduce (+bias/resid, f32 or bf16 out) ----------------

enum { RD_BIAS = 1, RD_RESID = 2, RD_BF16 = 4 };

template <int MODE>
__global__ void __launch_bounds__(256) reduce_k(const float* __restrict__ parts, int S,
                                                int MN, int N,
                                                const float* __restrict__ bias,
                                                const float* __restrict__ resid,
                                                void* __restrict__ out) {
  int i4 = (blockIdx.x * 256 + threadIdx.x) * 4;
  if (i4 >= MN) return;
  float4 a = *(const float4*)&parts[i4];
#pragma unroll 4
  for (int s = 1; s < S; s++) {
    float4 b = *(const float4*)&parts[(size_t)s * MN + i4];
    a.x += b.x; a.y += b.y; a.z += b.z; a.w += b.w;
  }
  if (MODE & RD_BIAS) {
    float4 b = *(const float4*)&bias[i4 & (N - 1)];
    a.x += b.x; a.y += b.y; a.z += b.z; a.w += b.w;
  }
  if (MODE & RD_RESID) {
    float4 b = *(const float4*)&resid[i4];
    a.x += b.x; a.y += b.y; a.z += b.z; a.w += b.w;
  }
  if (MODE & RD_BF16) {
    bf16 o[4] = {__float2bfloat16(a.x), __float2bfloat16(a.y),
                 __float2bfloat16(a.z), __float2bfloat16(a.w)};
    *(uint2*)&((bf16*)out)[i4] = *(uint2*)o;
  } else {
    *(float4*)&((float*)out)[i4] = a;
  }
}

// fused: sum 4 split-K planes + resid(lat) -> lat2(f32), then LN -> lnff(bf16)
__global__ void __launch_bounds__(256) reduce_ln_resid(
    const float* __restrict__ parts, const float* __restrict__ resid,
    const float* __restrict__ g, const float* __restrict__ bb,
    float* __restrict__ lat2, bf16* __restrict__ lnff) {
  __shared__ float red[8];
  int row = blockIdx.x, tid = threadIdx.x, c4 = tid * 4;
  const size_t MN = (size_t)2048 * 1024;
  size_t idx = (size_t)row * 1024 + c4;
  float4 p0 = *(const float4*)&parts[idx];
  float4 p1 = *(const float4*)&parts[MN + idx];
  float4 p2 = *(const float4*)&parts[2 * MN + idx];
  float4 p3 = *(const float4*)&parts[3 * MN + idx];
  float4 r2 = *(const float4*)&resid[idx];
  float4 a;
  a.x = p0.x + p1.x + p2.x + p3.x + r2.x;
  a.y = p0.y + p1.y + p2.y + p3.y + r2.y;
  a.z = p0.z + p1.z + p2.z + p3.z + r2.z;
  a.w = p0.w + p1.w + p2.w + p3.w + r2.w;
  *(float4*)&lat2[idx] = a;
  float mean, rstd;
  stats4(a, tid, mean, rstd, red);
  float4 gv = *(const float4*)&g[c4];
  float4 bv = *(const float4*)&bb[c4];
  pack4(&lnff[idx], (a.x - mean) * rstd * gv.x + bv.x,
        (a.y - mean) * rstd * gv.y + bv.y,
        (a.z - mean) * rstd * gv.z + bv.z,
        (a.w - mean) * rstd * gv.w + bv.w);
}

// fused epilogue: sum 4 planes + bias -> LN(nog,nob) -> f32 out (d_out)
__global__ void __launch_bounds__(256) reduce_bias_ln(
    const float* __restrict__ parts, const float* __restrict__ bias,
    const float* __restrict__ g, const float* __restrict__ bb,
    float* __restrict__ out) {
  __shared__ float red[8];
  int row = blockIdx.x, tid = threadIdx.x, c4 = tid * 4;
  const size_t MN = (size_t)2048 * 1024;
  size_t idx = (size_t)row * 1024 + c4;
  float4 p0 = *(const float4*)&parts[idx];
  float4 p1 = *(const float4*)&parts[MN + idx];
  float4 p2 = *(const float4*)&parts[2 * MN + idx];
  float4 p3 = *(const float4*)&parts[3 * MN + idx];
  float4 bv = *(const float4*)&bias[c4];
  float4 a;
  a.x = p0.x + p1.x + p2.x + p3.x + bv.x;
  a.y = p0.y + p1.y + p2.y + p3.y + bv.y;
  a.z = p0.z + p1.z + p2.z + p3.z + bv.z;
  a.w = p0.w + p1.w + p2.w + p3.w + bv.w;
  float mean, rstd;
  stats4(a, tid, mean, rstd, red);
  float4 gv = *(const float4*)&g[c4];
  float4 b2 = *(const float4*)&bb[c4];
  float4 o;
  o.x = (a.x - mean) * rstd * gv.x + b2.x;
  o.y = (a.y - mean) * rstd * gv.y + b2.y;
  o.z = (a.z - mean) * rstd * gv.z + b2.z;
  o.w = (a.w - mean) * rstd * gv.w + b2.w;
  *(float4*)&out[idx] = o;
}

// ---------------- fused attention: one block per (b,h) ----------------
// q: (b*64+m, h*64+d) bf16;  kv: (b*336+r, [k: h*64+d | v: 1024+h*64+d]) bf16
// valid kv rows: 321 (rows 321..335 are zero pad); scores scaled by 1/8.
//
// LDS: sQ/sKV are [64][64] bf16 with XOR granule swizzle
// byte ^= ((row&7)<<4) ^ (((row>>3)&3)<<5); sP stride 376 elems.

__device__ __forceinline__ int swz64(int row, int cb) {
  return (row << 7) + (cb ^ ((row & 7) << 4) ^ (((row >> 3) & 3) << 5));
}

__global__ void __launch_bounds__(256, 2) attn(const bf16* __restrict__ qb,
                                               const bf16* __restrict__ kvb,
                                               bf16* __restrict__ ob) {
  __shared__ bf16 sQ[64 * 64];
  __shared__ bf16 sKV[64 * 64];
  __shared__ bf16 sP[64 * 376];   // cols 0..351 used (336..351 zero)
  __shared__ float sRed[256];
  char* cQ = (char*)sQ;
  char* cKV = (char*)sKV;

  int h = blockIdx.x, b = blockIdx.y;
  int tid = threadIdx.x, wave = tid >> 6, lane = tid & 63;
  int quad = lane >> 4, l16 = lane & 15;

  const bf16* qg = qb + (size_t)b * 64 * 1024 + h * 64;
  const bf16* kg = kvb + (size_t)b * 336 * 2048 + h * 64;
  const bf16* vg = kg + 1024;

  {
    int r = tid >> 3, cb = (tid & 7) * 16;
    *(uint4*)(cQ + swz64(r, cb)) =
        *(const uint4*)((const char*)qg + (size_t)r * 2048 + cb);
    *(uint4*)(cQ + swz64(r + 32, cb)) =
        *(const uint4*)((const char*)qg + (size_t)(r + 32) * 2048 + cb);
  }

  f32x4 accS[6][4] = {};   // [kv group of 64][m-tile]; wave owns n-tile g*4+wave

  for (int g = 0; g < 6; g++) {
    __syncthreads();
    {
      int r = tid >> 3, cb = (tid & 7) * 16;
      int gr = g * 64 + r;
      if (gr < 336)
        *(uint4*)(cKV + swz64(r, cb)) =
            *(const uint4*)((const char*)kg + (size_t)gr * 4096 + cb);
      gr += 32;
      if (gr < 336)
        *(uint4*)(cKV + swz64(r + 32, cb)) =
            *(const uint4*)((const char*)kg + (size_t)gr * 4096 + cb);
    }
    __syncthreads();
    if (g * 4 + wave < 21) {
#pragma unroll
      for (int ks = 0; ks < 2; ks++) {
        short8 bfr = *(const short8*)(cKV + swz64(wave * 16 + l16, ks * 64 + quad * 16));
#pragma unroll
        for (int i = 0; i < 4; i++) {
          short8 afr = *(const short8*)(cQ + swz64(i * 16 + l16, ks * 64 + quad * 16));
          accS[g][i] = mfma16(afr, bfr, accS[g][i]);
        }
      }
    }
  }

  // ---- softmax over 321 valid cols ----
  float rmax[4][4], rsum[4][4];
#pragma unroll
  for (int i = 0; i < 4; i++)
#pragma unroll
    for (int r = 0; r < 4; r++) { rmax[i][r] = -1e30f; rsum[i][r] = 0.f; }

#pragma unroll
  for (int g = 0; g < 6; g++) {
    int col = (g * 4 + wave) * 16 + l16;
    bool valid = col < 321;
#pragma unroll
    for (int i = 0; i < 4; i++)
#pragma unroll
      for (int r = 0; r < 4; r++) {
        float v = accS[g][i][r] * 0.125f;   // (dh^-0.25)^2
        accS[g][i][r] = v;
        if (valid) rmax[i][r] = fmaxf(rmax[i][r], v);
      }
  }
#pragma unroll
  for (int off = 1; off < 16; off <<= 1)
#pragma unroll
    for (int i = 0; i < 4; i++)
#pragma unroll
      for (int r = 0; r < 4; r++)
        rmax[i][r] = fmaxf(rmax[i][r], __shfl_xor(rmax[i][r], off));
  if (l16 == 0) {
#pragma unroll
    for (int i = 0; i < 4; i++)
#pragma unroll
      for (int r = 0; r < 4; r++)
        sRed[wave * 64 + i * 16 + quad * 4 + r] = rmax[i][r];
  }
  __syncthreads();
#pragma unroll
  for (int i = 0; i < 4; i++)
#pragma unroll
    for (int r = 0; r < 4; r++) {
      int row = i * 16 + quad * 4 + r;
      rmax[i][r] = fmaxf(fmaxf(sRed[row], sRed[64 + row]),
                         fmaxf(sRed[128 + row], sRed[192 + row]));
    }
  __syncthreads();

#pragma unroll
  for (int g = 0; g < 6; g++) {
    int col = (g * 4 + wave) * 16 + l16;
    bool valid = col < 321;
#pragma unroll
    for (int i = 0; i < 4; i++)
#pragma unroll
      for (int r = 0; r < 4; r++) {
        float pv = valid ? __expf(accS[g][i][r] - rmax[i][r]) : 0.f;
        rsum[i][r] += pv;
        if (col < 352) sP[(i * 16 + quad * 4 + r) * 376 + col] = __float2bfloat16(pv);
      }
  }
#pragma unroll
  for (int off = 1; off < 16; off <<= 1)
#pragma unroll
    for (int i = 0; i < 4; i++)
#pragma unroll
      for (int r = 0; r < 4; r++)
        rsum[i][r] += __shfl_xor(rsum[i][r], off);
  if (l16 == 0) {
#pragma unroll
    for (int i = 0; i < 4; i++)
#pragma unroll
      for (int r = 0; r < 4; r++)
        sRed[wave * 64 + i * 16 + quad * 4 + r] = rsum[i][r];
  }
  __syncthreads();
#pragma unroll
  for (int i = 0; i < 4; i++)
#pragma unroll
    for (int r = 0; r < 4; r++) {
      int row = i * 16 + quad * 4 + r;
      rsum[i][r] = sRed[row] + sRed[64 + row] + sRed[128 + row] + sRed[192 + row];
    }

  // ---- O = P @ V, wave owns dh-tile [wave*16, wave*16+16) ----
  f32x4 accO[4] = {};
  for (int cch = 0; cch < 6; cch++) {
    __syncthreads();
    {
      int r = tid >> 3, cb = (tid & 7) * 16;
      int gr = cch * 64 + r;
      if (gr < 336)
        *(uint4*)(cKV + swz64(r, cb)) =
            *(const uint4*)((const char*)vg + (size_t)gr * 4096 + cb);
      gr += 32;
      if (gr < 336)
        *(uint4*)(cKV + swz64(r + 32, cb)) =
            *(const uint4*)((const char*)vg + (size_t)gr * 4096 + cb);
    }
    __syncthreads();
    int nks = (cch == 5) ? 1 : 2;   // last chunk: P zero past col 336
    for (int ks = 0; ks < nks; ks++) {
      short8 bv;
      int cb = (wave * 16 + l16) * 2;
#pragma unroll
      for (int jj = 0; jj < 8; jj++)
        bv[jj] = *(const short*)(cKV + swz64(ks * 32 + quad * 8 + jj, cb));
#pragma unroll
      for (int i = 0; i < 4; i++) {
        short8 ap = *(const short8*)&sP[(i * 16 + l16) * 376 + cch * 64 + ks * 32 + quad * 8];
        accO[i] = mfma16(ap, bv, accO[i]);
      }
    }
  }

#pragma unroll
  for (int i = 0; i < 4; i++)
#pragma unroll
    for (int r = 0; r < 4; r++) {
      int row = i * 16 + quad * 4 + r;
      ob[(size_t)(b * 64 + row) * 1024 + h * 64 + wave * 16 + l16] =
          __float2bfloat16(accO[i][r] / rsum[i][r]);
    }
}

// ---------------- host orchestration ----------------

extern "C" void kernel_launch(void* const* d_in, const int* in_sizes, int n_in,
                              void* d_out, int out_size, void* d_ws, size_t ws_size,
                              hipStream_t stream) {
  (void)in_sizes; (void)n_in; (void)out_size; (void)ws_size;
  const float* x    = (const float*)d_in[0];
  const float* lin  = (const float*)d_in[1];
  const float* piw  = (const float*)d_in[2];
  const float* pib  = (const float*)d_in[3];
  const float* ln1g = (const float*)d_in[4];
  const float* ln1b = (const float*)d_in[5];
  const float* ln2g = (const float*)d_in[6];
  const float* ln2b = (const float*)d_in[7];
  const float* Wq   = (const float*)d_in[8];
  const float* Wkv  = (const float*)d_in[9];
  const float* Wo   = (const float*)d_in[10];
  const float* ffg  = (const float*)d_in[11];
  const float* ffb  = (const float*)d_in[12];
  const float* W1   = (const float*)d_in[13];
  const float* W2   = (const float*)d_in[14];
  const float* poW  = (const float*)d_in[15];
  const float* pob  = (const float*)d_in[16];
  const float* nog  = (const float*)d_in[17];
  const float* nob  = (const float*)d_in[18];

  char* p = (char*)d_ws;
  auto alloc = [&](size_t bytes) -> char* {
    char* q = p; p += (bytes + 255) & ~(size_t)255; return q;
  };
  bf16* pin_t  = (bf16*)alloc((size_t)1024 * 768 * 2);
  bf16* pout_t = (bf16*)alloc((size_t)1024 * 1024 * 2);
  bf16* wq_t   = (bf16*)alloc((size_t)1024 * 1024 * 2);
  bf16* wkv_t  = (bf16*)alloc((size_t)2048 * 1024 * 2);
  bf16* wo_t   = (bf16*)alloc((size_t)1024 * 1024 * 2);
  bf16* w1_t   = (bf16*)alloc((size_t)4096 * 1024 * 2);
  bf16* w2_t   = (bf16*)alloc((size_t)1024 * 4096 * 2);
  bf16* x_bf   = (bf16*)alloc((size_t)8224 * 768 * 2);
  float* xf    = (float*)alloc((size_t)8224 * 1024 * 4);   // prologue xf; later: split-K partials
  bf16* xhat   = (bf16*)alloc((size_t)8224 * 1024 * 2);
  bf16* cat    = (bf16*)alloc((size_t)10752 * 1024 * 2);   // 32 x 336 rows
  bf16* lnlat  = (bf16*)alloc((size_t)2048 * 1024 * 2);
  bf16* qbuf   = (bf16*)alloc((size_t)2048 * 1024 * 2);
  bf16* kvbuf  = (bf16*)alloc((size_t)10752 * 2048 * 2);
  bf16* obuf   = (bf16*)alloc((size_t)2048 * 1024 * 2);
  float* lat   = (float*)alloc((size_t)2048 * 1024 * 4);
  float* lat2  = (float*)alloc((size_t)2048 * 1024 * 4);
  bf16* lnff   = (bf16*)alloc((size_t)2048 * 1024 * 2);
  bf16* h1     = (bf16*)alloc((size_t)2048 * 4096 * 2);

  const int MN = 2048 * 1024;   // split-K partial plane size

  // prologue
  cvt_f32_bf16<<<(6316032 / 4 + 255) / 256, 256, 0, stream>>>(x, x_bf, 6316032 / 4);
  transpose_cvt<<<dim3(16, 12), 256, 0, stream>>>(piw, pin_t, 768, 1024);
  transpose_cvt<<<dim3(16, 16), 256, 0, stream>>>(poW, pout_t, 1024, 1024);
  gemm_bt<MB_BIAS><<<dim3(8, 65), 256, 0, stream>>>(x_bf, pin_t, xf, pib, nullptr,
                                                    8224, 1024, 768);
  ln_to_bf16<<<8224, 256, 0, stream>>>(xf, nullptr, nullptr, xhat);

  for (int i = 0; i < 8; i++) {
    transpose_all<<<3072, 256, 0, stream>>>(
        Wq + (size_t)i * 1048576, Wkv + (size_t)i * 2097152, Wo + (size_t)i * 1048576,
        W1 + (size_t)i * 4194304, W2 + (size_t)i * 4194304,
        wq_t, wkv_t, wo_t, w1_t, w2_t);
    // lncat: layer 0 broadcasts lin -> lat; layers 1..7 also reduce prev ff2 planes
    if (i == 0)
      lncat<0><<<10752, 256, 0, stream>>>(xhat, lin, nullptr, nullptr, lat,
                                          ln1g + i * 1024, ln1b + i * 1024,
                                          ln2g + i * 1024, ln2b + i * 1024, cat, lnlat);
    else
      lncat<1><<<10752, 256, 0, stream>>>(xhat, nullptr, xf, lat2, lat,
                                          ln1g + i * 1024, ln1b + i * 1024,
                                          ln2g + i * 1024, ln2b + i * 1024, cat, lnlat);
    // kv = cat @ Wkv  (+ q = lnlat @ Wq appended as 128 extra tiles)
    gemm_qkv<<<dim3(16, 92), 256, 0, stream>>>(cat, wkv_t, kvbuf, lnlat, wq_t, qbuf);
    attn<<<dim3(16, 32), 256, 0, stream>>>(qbuf, kvbuf, obuf);
    // lat2 = o @ Wo + lat  (split-K=4), fused with ff-LN -> lnff
    gemm_bt<0><<<dim3(8, 16, 4), 256, 0, stream>>>(obuf, wo_t, xf, nullptr, nullptr,
                                                   2048, 1024, 1024);
    reduce_ln_resid<<<2048, 256, 0, stream>>>(xf, lat, ffg + i * 1024, ffb + i * 1024,
                                              lat2, lnff);
    gemm_bt<MB_GELU | MB_BF16><<<dim3(32, 16), 256, 0, stream>>>(lnff, w1_t, h1, nullptr,
                                                                 nullptr, 2048, 4096, 1024);
    // lat = h1 @ W2 + lat2  (split-K=4, Kper=1024); planes consumed by next lncat
    gemm_bt<0><<<dim3(8, 16, 4), 256, 0, stream>>>(h1, w2_t, xf, nullptr, nullptr,
                                                   2048, 1024, 4096);
    if (i == 7)   // final layer: fold reduce+resid straight to bf16 lnff
      reduce_k<RD_RESID | RD_BF16><<<MN / 1024, 256, 0, stream>>>(
          xf, 4, MN, 1024, nullptr, lat2, lnff);
  }

  // epilogue: proj_out + bias + final LN fused
  gemm_bt<0><<<dim3(8, 16, 4), 256, 0, stream>>>(lnff, pout_t, xf, nullptr, nullptr,
                                                 2048, 1024, 1024);
  reduce_bias_ln<<<2048, 256, 0, stream>>>(xf, pob, nog, nob, (float*)d_out);
}